// Round 4
// baseline (32.946 us; speedup 1.0000x reference)
//
#include <hip/hip_runtime.h>

typedef _Float16 half2v __attribute__((ext_vector_type(2)));
typedef _Float16 half8v __attribute__((ext_vector_type(8)));
typedef float floatx4 __attribute__((ext_vector_type(4)));

#define NBATCH 1024
#define NKSTEP 2048          // 65536 rules / 32
#define NKSPLIT 128
#define NMTILE 16            // 16 mtiles x 64 batches (4 rowblocks of 16)
#define KPW (NKSTEP / NKSPLIT)  // 16 ksteps per wave

// ws layout: ms = 32768 floats (128KB) | bfrag = 2MB | part = 128*1024 floats
#define MS_FLOATS 32768
#define BFRAG_BYTES ((size_t)NKSTEP * 64 * 16)

// ---- prep: B fragments (blocks 0..511) + memberships (blocks 512..639)
__global__ __launch_bounds__(256) void anfis_prep(
    const float* __restrict__ cw, const float* __restrict__ cb,
    const float* __restrict__ x, const float* __restrict__ mu,
    const float* __restrict__ sigma,
    half8v* __restrict__ bfrag, float* __restrict__ ms) {
  int bid = blockIdx.x;
  if (bid < 512) {
    int t = bid * 256 + threadIdx.x;       // 0..131071
    int kstep = t >> 6, l = t & 63;
    int g = l >> 4, col = l & 15;
    int rbase = kstep * 32 + g * 8;
    half8v o;
#pragma unroll
    for (int e = 0; e < 8; ++e) {
      int r = rbase + e;
      float v = (col < 8) ? cw[r * 8 + col] : ((col == 8) ? cb[r] : 0.0f);
      o[e] = (_Float16)v;
    }
    bfrag[t] = o;
  } else {
    int idx = (bid - 512) * 256 + threadIdx.x;   // 0..32767
    int b = idx >> 5, j = idx & 31, i = j >> 2;
    float s = fabsf(sigma[j]) + 1e-5f;
    float rs = __builtin_amdgcn_rcpf(s);
    float nv = -0.5f * rs * rs;
    float d = x[b * 8 + i] - mu[j];
    ms[idx] = __expf(d * d * nv);
  }
}

// ---- main: generated-A x Bfrag GEMM. 1 wave = 64 batches x 512 rules.
__global__ __launch_bounds__(64, 2) void anfis_main(
    const float* __restrict__ x, const float* __restrict__ ms,
    const half8v* __restrict__ bfrag, float* __restrict__ part) {
  int bid = blockIdx.x;
  int mtile = bid >> 7, ksplit = bid & 127;
  int l = threadIdx.x, g = l >> 4, col = l & 15;
  int u = g & 1, h = g >> 1;
  int d0 = (ksplit >> 5) & 3, d1 = (ksplit >> 3) & 3, d2 = (ksplit >> 1) & 3;
  int d3h = ksplit & 1;
  int b0 = mtile * 64;
  const half8v* Bp = bfrag + (size_t)ksplit * KPW * 64 + l;

  // per-rowblock context from precomputed memberships
  float pre[4], m3a[4], m3b[4], m5A[4], m5B[4];
  floatx4 m4v[4];
  half2v tab[4][4];
#pragma unroll
  for (int rb = 0; rb < 4; ++rb) {
    const float* base = ms + (size_t)(b0 + rb * 16 + col) * 32;
    pre[rb] = base[d0] * base[4 + d1] * base[8 + d2];
    float4 m3 = *(const float4*)(base + 12);
    m3a[rb] = d3h ? m3.z : m3.x;
    m3b[rb] = d3h ? m3.w : m3.y;
    m4v[rb] = *(const floatx4*)(base + 16);
    float4 m5 = *(const float4*)(base + 20);
    m5A[rb] = h ? m5.y : m5.x;
    m5B[rb] = h ? m5.w : m5.z;
    float4 m6 = *(const float4*)(base + 24);
    float m60 = u ? m6.z : m6.x;
    float m61 = u ? m6.w : m6.y;
    float4 m7 = *(const float4*)(base + 28);
    tab[rb][0] = (half2v){(_Float16)(m60 * m7.x), (_Float16)(m60 * m7.y)};
    tab[rb][1] = (half2v){(_Float16)(m60 * m7.z), (_Float16)(m60 * m7.w)};
    tab[rb][2] = (half2v){(_Float16)(m61 * m7.x), (_Float16)(m61 * m7.y)};
    tab[rb][3] = (half2v){(_Float16)(m61 * m7.z), (_Float16)(m61 * m7.w)};
  }

  floatx4 acc[4];
#pragma unroll
  for (int rb = 0; rb < 4; ++rb) acc[rb] = (floatx4){0.f, 0.f, 0.f, 0.f};

  // depth-2 B prefetch ring
  half8v bf[4];
  bf[0] = Bp[0];
  bf[1] = Bp[64];

#pragma unroll
  for (int j3 = 0; j3 < 2; ++j3) {         // d3 = d3h*2 + j3
    float p3[4];
#pragma unroll
    for (int rb = 0; rb < 4; ++rb) p3[rb] = pre[rb] * (j3 ? m3b[rb] : m3a[rb]);
#pragma unroll
    for (int j4 = 0; j4 < 4; ++j4) {       // d4 = j4
      float p4[4];
#pragma unroll
      for (int rb = 0; rb < 4; ++rb) p4[rb] = p3[rb] * m4v[rb][j4];
#pragma unroll
      for (int j01 = 0; j01 < 2; ++j01) {  // d5 = j01*2 + h
        int kk = j3 * 8 + j4 * 2 + j01;
        if (kk < KPW - 2) bf[(kk + 2) & 3] = Bp[(kk + 2) * 64];
        half8v b8 = bf[kk & 3];
#pragma unroll
        for (int rb = 0; rb < 4; ++rb) {
          float p5 = p4[rb] * (j01 ? m5B[rb] : m5A[rb]);
          _Float16 ph = (_Float16)p5;
          half2v pp = {ph, ph};
          half2v a0 = pp * tab[rb][0], a1 = pp * tab[rb][1],
                 a2 = pp * tab[rb][2], a3 = pp * tab[rb][3];
          half8v a8 = {a0.x, a0.y, a1.x, a1.y, a2.x, a2.y, a3.x, a3.y};
          acc[rb] = __builtin_amdgcn_mfma_f32_16x16x32_f16(a8, b8, acc[rb], 0, 0, 0);
        }
      }
    }
  }

  // epilogue: C[row=g*4+i][col], fold x, reduce over 16 cols
#pragma unroll
  for (int rb = 0; rb < 4; ++rb) {
#pragma unroll
    for (int i = 0; i < 4; ++i) {
      int bb = b0 + rb * 16 + g * 4 + i;
      float xc = 0.0f;
      if (col < 8) xc = x[bb * 8 + col];
      else if (col == 8) xc = 1.0f;
      float v = acc[rb][i] * xc;
      v += __shfl_xor(v, 1);
      v += __shfl_xor(v, 2);
      v += __shfl_xor(v, 4);
      v += __shfl_xor(v, 8);
      if (col == 0) part[ksplit * NBATCH + bb] = v;
    }
  }
}

// ---- final: reduce k-splits, divide by separable denominator (from ms)
__global__ __launch_bounds__(256) void anfis_final(
    const float* __restrict__ part, const float* __restrict__ ms,
    float* __restrict__ out) {
  int b = blockIdx.x * 256 + threadIdx.x;
  float s = 0.0f;
#pragma unroll 8
  for (int ks = 0; ks < NKSPLIT; ++ks) s += part[ks * NBATCH + b];
  const float* base = ms + (size_t)b * 32;
  float den = 1.0f;
#pragma unroll
  for (int i = 0; i < 8; ++i) {
    float4 m = *(const float4*)(base + i * 4);
    den *= (m.x + m.y + m.z + m.w);
  }
  out[b] = s / (den + 1e-6f);
}

extern "C" void kernel_launch(void* const* d_in, const int* in_sizes, int n_in,
                              void* d_out, int out_size, void* d_ws, size_t ws_size,
                              hipStream_t stream) {
  const float* x     = (const float*)d_in[0];
  const float* mu    = (const float*)d_in[1];
  const float* sigma = (const float*)d_in[2];
  const float* cw    = (const float*)d_in[3];
  const float* cb    = (const float*)d_in[4];
  float* ms = (float*)d_ws;
  half8v* bfrag = (half8v*)((char*)d_ws + MS_FLOATS * 4);
  float* part = (float*)((char*)d_ws + MS_FLOATS * 4 + BFRAG_BYTES);
  float* out = (float*)d_out;

  anfis_prep<<<640, 256, 0, stream>>>(cw, cb, x, mu, sigma, bfrag, ms);
  anfis_main<<<NMTILE * NKSPLIT, 64, 0, stream>>>(x, ms, bfrag, part);
  anfis_final<<<4, 256, 0, stream>>>(part, ms, out);
}

// Round 6
// 20.912 us; speedup vs baseline: 1.5755x; 1.5755x over previous
//
#include <hip/hip_runtime.h>

typedef _Float16 half2v __attribute__((ext_vector_type(2)));
typedef _Float16 half8v __attribute__((ext_vector_type(8)));
typedef float floatx4 __attribute__((ext_vector_type(4)));

#define NBATCH 1024
#define NKSPLIT 128
#define KPW 16            // k-steps (of 32 rules) per wave
#define NMTILE 16         // 16 mtiles x 64 batches

__device__ __forceinline__ float sel4(float a0, float a1, float a2, float a3, int d) {
  float r = (d == 1) ? a1 : a0;
  r = (d == 2) ? a2 : r;
  r = (d == 3) ? a3 : r;
  return r;
}

__device__ __forceinline__ half2v cvt2h(float a, float b) {
  return __builtin_bit_cast(half2v, __builtin_amdgcn_cvt_pkrtz(a, b));
}

// ---- main: generated-A x (gathered, in-wave-converted B) GEMM.
// 1 wave = 64 batches x 512 rules. grid = 16 mtiles x 128 ksplits = 2048 waves.
__global__ __launch_bounds__(64, 2) void anfis_main(
    const float* __restrict__ x, const float* __restrict__ mu,
    const float* __restrict__ sigma, const float* __restrict__ cw,
    const float* __restrict__ cb, float* __restrict__ part) {
  const int bid = blockIdx.x;
  const int mtile = bid >> 7, ksplit = bid & (NKSPLIT - 1);
  const int l = threadIdx.x, g = l >> 4, col = l & 15;
  const int u = g & 1, h = g >> 1;
  const int d0 = (ksplit >> 5) & 3, d1 = (ksplit >> 3) & 3, d2 = (ksplit >> 1) & 3;
  const int d3h = ksplit & 1;
  const int b0 = mtile * 64;
  const int r0 = ksplit * (KPW * 32) + g * 8;   // rule of (kk=0, e=0) for this lane

  // per-lane B gather base + strides (col<8: cw column; col==8: cb; col>8: zeroed)
  const bool isw = (col < 8);
  const bool isvalid = (col <= 8);
  const float* gp = isw ? (cw + (size_t)r0 * 8 + col) : (cb + r0);
  const int es = isw ? 8 : 1;        // floats per rule
  const int ks = isw ? 256 : 32;     // floats per k-step

  // prefetch first 4 k-steps of B (latency hides under the exp prologue)
  float fv[4][8];
#pragma unroll
  for (int kk = 0; kk < 4; ++kk)
#pragma unroll
    for (int e = 0; e < 8; ++e)
      fv[kk][e] = gp[kk * ks + e * es];

  // wave-uniform sigma-derived scales (hoisted out of the rb loop)
  float nv[32];
#pragma unroll
  for (int j = 0; j < 32; ++j) {
    float s_ = fabsf(sigma[j]) + 1e-5f;
    float rs = __builtin_amdgcn_rcpf(s_);
    nv[j] = -0.5f * rs * rs;
  }

  // per-rowblock membership context, fully in registers
  float pre[4], m3a[4], m3b[4], m5A[4], m5B[4];
  floatx4 m4v[4];
  half2v tab[4][4];
#pragma unroll
  for (int rb = 0; rb < 4; ++rb) {
    const int bb = b0 + rb * 16 + col;
    const float4* xv = (const float4*)(x + bb * 8);
    float4 xa = xv[0], xb = xv[1];
    float xs8[8] = {xa.x, xa.y, xa.z, xa.w, xb.x, xb.y, xb.z, xb.w};
    float msD[8][4];
#pragma unroll
    for (int i = 0; i < 8; ++i)
#pragma unroll
      for (int q = 0; q < 4; ++q) {
        float d = xs8[i] - mu[i * 4 + q];
        msD[i][q] = __expf(d * d * nv[i * 4 + q]);
      }
    pre[rb] = sel4(msD[0][0], msD[0][1], msD[0][2], msD[0][3], d0) *
              sel4(msD[1][0], msD[1][1], msD[1][2], msD[1][3], d1) *
              sel4(msD[2][0], msD[2][1], msD[2][2], msD[2][3], d2);
    m3a[rb] = d3h ? msD[3][2] : msD[3][0];
    m3b[rb] = d3h ? msD[3][3] : msD[3][1];
    m4v[rb] = (floatx4){msD[4][0], msD[4][1], msD[4][2], msD[4][3]};
    m5A[rb] = h ? msD[5][1] : msD[5][0];
    m5B[rb] = h ? msD[5][3] : msD[5][2];
    float m60 = u ? msD[6][2] : msD[6][0];
    float m61 = u ? msD[6][3] : msD[6][1];
    tab[rb][0] = cvt2h(m60 * msD[7][0], m60 * msD[7][1]);
    tab[rb][1] = cvt2h(m60 * msD[7][2], m60 * msD[7][3]);
    tab[rb][2] = cvt2h(m61 * msD[7][0], m61 * msD[7][1]);
    tab[rb][3] = cvt2h(m61 * msD[7][2], m61 * msD[7][3]);
  }

  floatx4 acc[4];
#pragma unroll
  for (int rb = 0; rb < 4; ++rb) acc[rb] = (floatx4){0.f, 0.f, 0.f, 0.f};

#pragma unroll
  for (int kk = 0; kk < KPW; ++kk) {
    const int j3 = kk >> 3, j4 = (kk >> 1) & 3, j01 = kk & 1;
    // pack current B fragment (f32 -> f16 pairs)
    half2v b01 = cvt2h(fv[kk & 3][0], fv[kk & 3][1]);
    half2v b23 = cvt2h(fv[kk & 3][2], fv[kk & 3][3]);
    half2v b45 = cvt2h(fv[kk & 3][4], fv[kk & 3][5]);
    half2v b67 = cvt2h(fv[kk & 3][6], fv[kk & 3][7]);
    const half2v z2 = {(_Float16)0.0f, (_Float16)0.0f};
    b01 = isvalid ? b01 : z2;
    b23 = isvalid ? b23 : z2;
    b45 = isvalid ? b45 : z2;
    b67 = isvalid ? b67 : z2;
    half8v b8 = {b01.x, b01.y, b23.x, b23.y, b45.x, b45.y, b67.x, b67.y};
    // prefetch k-step kk+4 into the slot just consumed
    if (kk + 4 < KPW) {
#pragma unroll
      for (int e = 0; e < 8; ++e)
        fv[kk & 3][e] = gp[(kk + 4) * ks + e * es];
    }
    // generate A and accumulate
#pragma unroll
    for (int rb = 0; rb < 4; ++rb) {
      float p3 = pre[rb] * (j3 ? m3b[rb] : m3a[rb]);
      float p4 = p3 * m4v[rb][j4];                    // j4 is compile-time
      float p5 = p4 * (j01 ? m5B[rb] : m5A[rb]);
      _Float16 ph = (_Float16)p5;
      half2v pp = {ph, ph};
      half2v a0 = pp * tab[rb][0], a1 = pp * tab[rb][1],
             a2 = pp * tab[rb][2], a3 = pp * tab[rb][3];
      half8v a8 = {a0.x, a0.y, a1.x, a1.y, a2.x, a2.y, a3.x, a3.y};
      acc[rb] = __builtin_amdgcn_mfma_f32_16x16x32_f16(a8, b8, acc[rb], 0, 0, 0);
    }
  }

  // epilogue: C[row=g*4+i][col], fold x, reduce over 16 cols
#pragma unroll
  for (int rb = 0; rb < 4; ++rb) {
#pragma unroll
    for (int i = 0; i < 4; ++i) {
      int bb = b0 + rb * 16 + g * 4 + i;
      float xc = 0.0f;
      if (col < 8) xc = x[bb * 8 + col];
      else if (col == 8) xc = 1.0f;
      float v = acc[rb][i] * xc;
      v += __shfl_xor(v, 1);
      v += __shfl_xor(v, 2);
      v += __shfl_xor(v, 4);
      v += __shfl_xor(v, 8);
      if (col == 0) part[ksplit * NBATCH + bb] = v;
    }
  }
}

// ---- final: reduce 128 k-splits per batch + analytic separable denominator.
// 64 blocks x 256 threads; block owns 16 batches; thread sums 8 parts.
__global__ __launch_bounds__(256) void anfis_final(
    const float* __restrict__ part, const float* __restrict__ x,
    const float* __restrict__ mu, const float* __restrict__ sigma,
    float* __restrict__ out) {
  const int t = threadIdx.x;
  const int bloc = t & 15;
  const int chunk = t >> 4;     // 0..15, each covers 8 ksplits
  const int b = blockIdx.x * 16 + bloc;

  float s = 0.0f;
#pragma unroll
  for (int j = 0; j < 8; ++j)
    s += part[(chunk * 8 + j) * NBATCH + b];   // coalesced across bloc

  __shared__ float red[16][17];
  red[chunk][bloc] = s;
  __syncthreads();

  if (t < 16) {
    const int bb = blockIdx.x * 16 + t;
    float tot = 0.0f;
#pragma unroll
    for (int c = 0; c < 16; ++c) tot += red[c][t];
    const float4* xv = (const float4*)(x + bb * 8);
    float4 xa = xv[0], xb = xv[1];
    float xs8[8] = {xa.x, xa.y, xa.z, xa.w, xb.x, xb.y, xb.z, xb.w};
    float den = 1.0f;
#pragma unroll
    for (int i = 0; i < 8; ++i) {
      float rowsum = 0.0f;
#pragma unroll
      for (int q = 0; q < 4; ++q) {
        float s_ = fabsf(sigma[i * 4 + q]) + 1e-5f;
        float rs = __builtin_amdgcn_rcpf(s_);
        float nvq = -0.5f * rs * rs;
        float d = xs8[i] - mu[i * 4 + q];
        rowsum += __expf(d * d * nvq);
      }
      den *= rowsum;
    }
    out[bb] = tot / (den + 1e-6f);
  }
}

extern "C" void kernel_launch(void* const* d_in, const int* in_sizes, int n_in,
                              void* d_out, int out_size, void* d_ws, size_t ws_size,
                              hipStream_t stream) {
  const float* x     = (const float*)d_in[0];
  const float* mu    = (const float*)d_in[1];
  const float* sigma = (const float*)d_in[2];
  const float* cw    = (const float*)d_in[3];
  const float* cb    = (const float*)d_in[4];
  float* part = (float*)d_ws;       // 128 * 1024 floats = 512 KB
  float* out = (float*)d_out;

  anfis_main<<<NMTILE * NKSPLIT, 64, 0, stream>>>(x, mu, sigma, cw, cb, part);
  anfis_final<<<NBATCH / 16, 256, 0, stream>>>(part, x, mu, sigma, out);
}